// Round 18
// baseline (316.258 us; speedup 1.0000x reference)
//
#include <hip/hip_runtime.h>

typedef unsigned short u16;
typedef __attribute__((ext_vector_type(8))) short bf16x8;
typedef __attribute__((ext_vector_type(4))) float f32x4;

#define MFMA16(a,b,c) __builtin_amdgcn_mfma_f32_16x16x32_bf16(a,b,c,0,0,0)

// ---- constants ----
#define DMODEL   1024
#define DINNER   2048
#define NHEADS   32
#define HEADDIM  64
#define GDIM     128
#define DXBC     10240
#define DPROJ    12320
#define CHUNK_L  128
#define NCHUNK   16
#define NROWS    4096

__device__ __forceinline__ float b2f(u16 u){ return __uint_as_float(((unsigned)u)<<16); }
__device__ __forceinline__ u16 f2b(float f){
  unsigned u = __float_as_uint(f);
  u += 0x7fffu + ((u>>16)&1u);
  return (u16)(u>>16);
}

__device__ __forceinline__ void gload_lds16(const void* g, void* l){
  __builtin_amdgcn_global_load_lds(
      (const __attribute__((address_space(1))) unsigned int*)g,
      (__attribute__((address_space(3))) unsigned int*)l, 16, 0, 0);
}

// ---------------- K0: prologue merge — weight f2b (blocks <2048) + input RMSNorm (>=2048) ----------------
__global__ __launch_bounds__(256) void k_prep(const float* __restrict__ s1, u16* __restrict__ d1, int n1,
                                              const float* __restrict__ s2, u16* __restrict__ d2, int n2,
                                              const float* __restrict__ x, const float* __restrict__ w,
                                              u16* __restrict__ u){
  __shared__ float red[4];
  if (blockIdx.x < 2048){
    int i = blockIdx.x*256 + threadIdx.x;
    int stride = 2048*256;
    int t1 = n1 >> 2, t2 = n2 >> 2;
    for (int j=i; j<t1+t2; j+=stride){
      const float4* sp; uint2* dp; int idx;
      if (j < t1){ sp = (const float4*)s1; dp = (uint2*)d1; idx = j; }
      else       { sp = (const float4*)s2; dp = (uint2*)d2; idx = j - t1; }
      float4 v = sp[idx];
      uint2 o;
      o.x = (unsigned)f2b(v.x) | ((unsigned)f2b(v.y)<<16);
      o.y = (unsigned)f2b(v.z) | ((unsigned)f2b(v.w)<<16);
      dp[idx] = o;
    }
  } else {
    int row = blockIdx.x - 2048, tid = threadIdx.x;
    float4 v = reinterpret_cast<const float4*>(x + (size_t)row*DMODEL)[tid];
    float ss = v.x*v.x + v.y*v.y + v.z*v.z + v.w*v.w;
    #pragma unroll
    for (int off=32; off>0; off>>=1) ss += __shfl_down(ss, off, 64);
    if ((tid&63)==0) red[tid>>6] = ss;
    __syncthreads();
    float tot = red[0]+red[1]+red[2]+red[3];
    float sc = rsqrtf(tot/(float)DMODEL + 1e-5f);
    float4 wv = reinterpret_cast<const float4*>(w)[tid];
    uint2 o;
    o.x = (unsigned)f2b(v.x*wv.x*sc) | ((unsigned)f2b(v.y*wv.y*sc)<<16);
    o.y = (unsigned)f2b(v.z*wv.z*sc) | ((unsigned)f2b(v.w*wv.w*sc)<<16);
    reinterpret_cast<uint2*>(u + (size_t)row*DMODEL)[tid] = o;
  }
}

// ======== GEMM1: 256x256 tile, BK=64, 8 waves, 4-phase, counted vmcnt ========
// Epilogue: acc -> LDS (swizzle col^((row&7)<<3)) -> 16B coalesced stores.
__global__ __launch_bounds__(512) void k_gemm1_8p(const u16* __restrict__ A,
                                                  const u16* __restrict__ W,
                                                  u16* __restrict__ zb,
                                                  u16* __restrict__ xbc){
  __shared__ __align__(16) u16 lds[65536];     // 128 KB
  const int tid  = threadIdx.x;
  const int lane = tid & 63, w = tid >> 6;
  const int wr = w >> 2, wc = w & 3;
  int bid = blockIdx.x;
  int xcd = bid & 7, g = bid >> 3;
  int st  = xcd*6 + (g >> 4);
  int wi  = g & 15;
  int tm  = (st/12)*4 + (wi>>2);
  int tn  = (st%12)*4 + (wi&3);
  const int m0 = tm*256, n0 = tn*256;

  const int srow = w*8 + (lane>>3);
  const int scol = ((lane&7) ^ ((lane>>3)&7))*8;
  const u16* aS = A + (size_t)(m0 + srow)*DMODEL + scol;
  const u16* bS = W + (size_t)(n0 + srow)*DMODEL + scol;
  const int ldsw = w*512;

  const int rr = lane & 15, gq = lane >> 4;

  f32x4 acc[8][4];
  #pragma unroll
  for (int i=0;i<8;i++)
    #pragma unroll
    for (int j=0;j<4;j++) acc[i][j] = (f32x4){0,0,0,0};

  auto SU_A = [&](int kt, int j){
    gload_lds16(aS + (size_t)(j*64)*DMODEL + kt*64,
                lds + (kt&1)*32768 + j*4096 + ldsw);
  };
  auto SU_B = [&](int kt, int j){
    gload_lds16(bS + (size_t)(j*64)*DMODEL + kt*64,
                lds + (kt&1)*32768 + 16384 + j*4096 + ldsw);
  };

  SU_A(0,0); SU_A(0,2); SU_B(0,0); SU_B(0,2); SU_B(0,1); SU_B(0,3); SU_A(0,1); SU_A(0,3);
  asm volatile("s_waitcnt vmcnt(2)" ::: "memory");
  __builtin_amdgcn_s_barrier();
  __builtin_amdgcn_sched_barrier(0);

  for (int kt = 0; kt < 16; ++kt){
    const u16* bufA = lds + (kt&1)*32768;
    const u16* bufB = bufA + 16384;
    const bool stg = (kt < 15);
    bf16x8 af[4][2], bw0[2][2], bw1[2][2];

    auto RDA = [&](int ti, int ks)->bf16x8{
      int r = wr*128 + ti*16 + rr;
      int s = (ks*4 + gq) ^ (rr & 7);
      return *(const bf16x8*)&bufA[r*64 + s*8];
    };
    auto RDB = [&](int tj, int ks)->bf16x8{
      int r = wc*64 + tj*16 + rr;
      int s = (ks*4 + gq) ^ (rr & 7);
      return *(const bf16x8*)&bufB[r*64 + s*8];
    };

    // phase 1
    #pragma unroll
    for (int ti=0;ti<4;ti++){ af[ti][0]=RDA(ti,0); af[ti][1]=RDA(ti,1); }
    #pragma unroll
    for (int tj=0;tj<2;tj++){ bw0[tj][0]=RDB(tj,0); bw0[tj][1]=RDB(tj,1); }
    if (stg){ SU_A(kt+1,0); SU_A(kt+1,2); }
    __builtin_amdgcn_s_barrier();
    asm volatile("s_waitcnt lgkmcnt(0)" ::: "memory");
    __builtin_amdgcn_sched_barrier(0);
    __builtin_amdgcn_s_setprio(1);
    #pragma unroll
    for (int ti=0;ti<4;ti++)
      #pragma unroll
      for (int tj=0;tj<2;tj++){
        acc[ti][tj] = MFMA16(af[ti][0], bw0[tj][0], acc[ti][tj]);
        acc[ti][tj] = MFMA16(af[ti][1], bw0[tj][1], acc[ti][tj]);
      }
    __builtin_amdgcn_s_setprio(0);
    __builtin_amdgcn_s_barrier();

    // phase 2
    #pragma unroll
    for (int tj=0;tj<2;tj++){ bw1[tj][0]=RDB(tj+2,0); bw1[tj][1]=RDB(tj+2,1); }
    if (stg){ SU_B(kt+1,0); SU_B(kt+1,2); }
    __builtin_amdgcn_s_barrier();
    asm volatile("s_waitcnt lgkmcnt(0)" ::: "memory");
    __builtin_amdgcn_sched_barrier(0);
    __builtin_amdgcn_s_setprio(1);
    #pragma unroll
    for (int ti=0;ti<4;ti++)
      #pragma unroll
      for (int tj=0;tj<2;tj++){
        acc[ti][tj+2] = MFMA16(af[ti][0], bw1[tj][0], acc[ti][tj+2]);
        acc[ti][tj+2] = MFMA16(af[ti][1], bw1[tj][1], acc[ti][tj+2]);
      }
    __builtin_amdgcn_s_setprio(0);
    if (stg) asm volatile("s_waitcnt vmcnt(4)" ::: "memory");
    else     asm volatile("s_waitcnt vmcnt(0)" ::: "memory");
    __builtin_amdgcn_s_barrier();

    // phase 3
    #pragma unroll
    for (int ti=0;ti<4;ti++){ af[ti][0]=RDA(ti+4,0); af[ti][1]=RDA(ti+4,1); }
    if (stg){ SU_B(kt+1,1); SU_B(kt+1,3); }
    __builtin_amdgcn_s_barrier();
    asm volatile("s_waitcnt lgkmcnt(0)" ::: "memory");
    __builtin_amdgcn_sched_barrier(0);
    __builtin_amdgcn_s_setprio(1);
    #pragma unroll
    for (int ti=0;ti<4;ti++)
      #pragma unroll
      for (int tj=0;tj<2;tj++){
        acc[4+ti][tj] = MFMA16(af[ti][0], bw0[tj][0], acc[4+ti][tj]);
        acc[4+ti][tj] = MFMA16(af[ti][1], bw0[tj][1], acc[4+ti][tj]);
      }
    __builtin_amdgcn_s_setprio(0);
    __builtin_amdgcn_s_barrier();

    // phase 4
    if (stg){ SU_A(kt+1,1); SU_A(kt+1,3); }
    __builtin_amdgcn_s_barrier();
    __builtin_amdgcn_sched_barrier(0);
    __builtin_amdgcn_s_setprio(1);
    #pragma unroll
    for (int ti=0;ti<4;ti++)
      #pragma unroll
      for (int tj=0;tj<2;tj++){
        acc[4+ti][tj+2] = MFMA16(af[ti][0], bw1[tj][0], acc[4+ti][tj+2]);
        acc[4+ti][tj+2] = MFMA16(af[ti][1], bw1[tj][1], acc[4+ti][tj+2]);
      }
    __builtin_amdgcn_s_setprio(0);
    if (stg){
      asm volatile("s_waitcnt vmcnt(2)" ::: "memory");
      __builtin_amdgcn_s_barrier();
      __builtin_amdgcn_sched_barrier(0);
    }
  }

  // ---- epilogue: acc -> LDS transpose -> vectorized stores ----
  // Safe to write LDS here: all waves' ds_reads completed before their last in-loop barrier.
  #pragma unroll
  for (int ti=0;ti<8;ti++)
    #pragma unroll
    for (int tj=0;tj<4;tj++)
      #pragma unroll
      for (int q=0;q<4;q++){
        int rl = wr*128 + ti*16 + (lane>>4)*4 + q;
        int cl = wc*64 + tj*16 + (lane&15);
        lds[rl*256 + (cl ^ ((rl&7)<<3))] = f2b(acc[ti][tj][q]);
      }
  __syncthreads();
  u16* dst; size_t dstride; int dcol;
  if (tn >= 8){ dst = xbc; dstride = DXBC;   dcol = n0 - DINNER; }
  else        { dst = zb;  dstride = DINNER; dcol = n0; }
  {
    int r  = tid & 255;
    int hb = (tid >> 8) * 128;
    u16* drow = dst + (size_t)(m0 + r)*dstride + dcol + hb;
    #pragma unroll
    for (int i=0;i<16;i++){
      int c = hb + i*8;
      uint4 v = *(const uint4*)&lds[r*256 + (c ^ ((r&7)<<3))];
      *(uint4*)&drow[i*8] = v;
    }
  }
}

// ---------------- K2b: GEMM1 dt strip (cols 12288..12319), K-split over waves ----------------
__global__ __launch_bounds__(256) void k_gemm_dt(const u16* __restrict__ A,
                                                 const u16* __restrict__ W,
                                                 float* __restrict__ dtraw){
  const int lane = threadIdx.x & 63, wv = threadIdx.x >> 6;
  const int m0 = blockIdx.x*32;
  const int n0 = DINNER + DXBC;   // 12288
  const int r  = lane & 15;
  const int kb = (lane>>4)*8;
  const int k0 = wv*256;
  const u16* a0p = A + (size_t)(m0 + r)*DMODEL + k0 + kb;
  const u16* a1p = a0p + 16*DMODEL;
  const u16* b0p = W + (size_t)(n0 + r)*DMODEL + k0 + kb;
  const u16* b1p = b0p + 16*DMODEL;
  f32x4 acc00={0,0,0,0}, acc01={0,0,0,0}, acc10={0,0,0,0}, acc11={0,0,0,0};
  #pragma unroll
  for (int k=0;k<256;k+=32){
    bf16x8 a0 = *(const bf16x8*)(a0p + k);
    bf16x8 a1 = *(const bf16x8*)(a1p + k);
    bf16x8 b0 = *(const bf16x8*)(b0p + k);
    bf16x8 b1 = *(const bf16x8*)(b1p + k);
    acc00 = MFMA16(a0,b0,acc00);
    acc01 = MFMA16(a0,b1,acc01);
    acc10 = MFMA16(a1,b0,acc10);
    acc11 = MFMA16(a1,b1,acc11);
  }
  __shared__ float part[4][1024];
  int rowb = (lane>>4)*4, col = lane&15;
  #pragma unroll
  for (int rr=0; rr<4; rr++){
    part[wv][(rowb+rr)*32 + col]         = acc00[rr];
    part[wv][(rowb+rr)*32 + col+16]      = acc01[rr];
    part[wv][(rowb+16+rr)*32 + col]      = acc10[rr];
    part[wv][(rowb+16+rr)*32 + col+16]   = acc11[rr];
  }
  __syncthreads();
  int idx = threadIdx.x*4;
  #pragma unroll
  for (int q=0;q<4;q++){
    int i = idx+q;
    dtraw[(size_t)m0*NHEADS + i] = part[0][i]+part[1][i]+part[2][i]+part[3][i];
  }
}

// ---------------- K3+K4 merged launch: conv (blocks <1280, 8 chan/thread) + dtscan (>=1280) ----------------
__global__ __launch_bounds__(256) void k_convdt(const u16* __restrict__ xbc,
                                                const float* __restrict__ cw,
                                                const float* __restrict__ cb,
                                                u16* __restrict__ xh,
                                                u16* __restrict__ Bm,
                                                u16* __restrict__ Cm,
                                                const float* __restrict__ dtraw,
                                                const float* __restrict__ dt_bias,
                                                const float* __restrict__ A_log,
                                                float* __restrict__ dtT,
                                                float* __restrict__ cumT){
  __shared__ float lds2[2][128];
  int tid = threadIdx.x;
  if (blockIdx.x < 1280){
    // conv: 8 channels/thread (uint4 loads/stores), 16 rows rolling window
    int cblk = blockIdx.x;
    int cx = cblk % 5, ry = cblk / 5;
    int c0 = (cx*256 + tid)*8;
    int row0 = ry*16;
    int l0 = row0 & 2047;
    float4 w4[8]; float cbv[8];
    #pragma unroll
    for (int j=0;j<8;j++){ w4[j] = reinterpret_cast<const float4*>(cw)[c0+j]; cbv[j] = cb[c0+j]; }
    float p3[8]={0,0,0,0,0,0,0,0}, p2[8]={0,0,0,0,0,0,0,0}, p1[8]={0,0,0,0,0,0,0,0};
    auto loadoct = [&](int rw, float q[8]){
      uint4 v = *(const uint4*)&xbc[(size_t)rw*DXBC + c0];
      const u16* pv = (const u16*)&v;
      #pragma unroll
      for (int j=0;j<8;j++) q[j] = b2f(pv[j]);
    };
    if (l0 >= 3){ loadoct(row0-3,p3); loadoct(row0-2,p2); loadoct(row0-1,p1); }
    #pragma unroll
    for (int i=0;i<16;i++){
      float cur[8]; loadoct(row0+i, cur);
      u16 o[8];
      #pragma unroll
      for (int j=0;j<8;j++){
        float s = cbv[j] + p3[j]*w4[j].x + p2[j]*w4[j].y + p1[j]*w4[j].z + cur[j]*w4[j].w;
        o[j] = f2b(s/(1.f+expf(-s)));
      }
      uint4 ov = *(const uint4*)o;
      int rw = row0 + i;
      if (c0 < DINNER)            *(uint4*)&xh[(size_t)rw*DINNER + c0] = ov;
      else if (c0 < DINNER+4096)  *(uint4*)&Bm[(size_t)rw*4096 + (c0-DINNER)] = ov;
      else                        *(uint4*)&Cm[(size_t)rw*4096 + (c0-DINNER-4096)] = ov;
      #pragma unroll
      for (int j=0;j<8;j++){ p3[j]=p2[j]; p2[j]=p1[j]; p1[j]=cur[j]; }
    }
  } else {
    // dtscan: two (bc,h) scans per block (128 threads each)
    int half = tid >> 7;
    int blk  = (blockIdx.x - 1280)*2 + half;   // 0..1023
    int h  = blk & 31;
    int bc = blk >> 5;
    int s  = tid & 127;
    int row = bc*128 + s;
    float xv = dtraw[(size_t)row*NHEADS + h] + dt_bias[h];
    float dt = (xv > 20.f) ? xv : log1pf(expf(xv));
    float a  = dt * (-expf(A_log[h]));
    lds2[half][s] = a; __syncthreads();
    #pragma unroll
    for (int off=1; off<128; off<<=1){
      float t = (s>=off) ? lds2[half][s-off] : 0.f;
      __syncthreads();
      lds2[half][s] += t;
      __syncthreads();
    }
    dtT[(size_t)blk*128 + s]  = dt;
    cumT[(size_t)blk*128 + s] = lds2[half][s];
  }
}

// ---------------- K5: chunk states S[g][p] (bf16), 512 threads, 8 waves ----------------
__global__ __launch_bounds__(512) void k_states(const u16* __restrict__ Bm,
                                                const u16* __restrict__ xh,
                                                const float* __restrict__ dtT,
                                                const float* __restrict__ cumT,
                                                u16* __restrict__ S){
  int blk = blockIdx.x;
  int h = blk & 31, bc = blk >> 5;
  __shared__ __align__(16) u16 Bw[128][136];
  __shared__ __align__(16) u16 XT[64][136];
  __shared__ float cum[128], dtv[128];
  int tid = threadIdx.x;
  if (tid < 128){ cum[tid] = cumT[(size_t)blk*128+tid]; dtv[tid] = dtT[(size_t)blk*128+tid]; }
  __syncthreads();
  float clast = cum[127];
  #pragma unroll
  for (int it=0; it<4; ++it){
    int s  = it*32 + (tid>>4);
    int g8 = (tid&15)*8;
    uint4 v = *(const uint4*)&Bm[(size_t)(bc*128+s)*4096 + h*128 + g8];
    float w = expf(clast - cum[s]) * dtv[s];
    const u16* pv = (const u16*)&v;
    #pragma unroll
    for (int j=0;j<8;j++) Bw[g8+j][s] = f2b(b2f(pv[j]) * w);
  }
  #pragma unroll
  for (int it=0; it<4; ++it){
    int s  = it*32 + (tid>>4);
    int p4 = (tid&15)*4;
    uint2 v = *(const uint2*)&xh[(size_t)(bc*128+s)*DINNER + h*64 + p4];
    const u16* pv = (const u16*)&v;
    #pragma unroll
    for (int j=0;j<4;j++) XT[p4+j][s] = pv[j];
  }
  __syncthreads();
  int lane = tid & 63, wv = tid >> 6;
  int r = lane & 15, kb = (lane>>4)*8;
  f32x4 acc[4];
  #pragma unroll
  for (int j=0;j<4;j++) acc[j] = (f32x4){0,0,0,0};
  #pragma unroll
  for (int k=0;k<128;k+=32){
    bf16x8 a0 = *(const bf16x8*)&Bw[wv*16 + r][k+kb];
    #pragma unroll
    for (int tj=0;tj<4;tj++){
      bf16x8 bb = *(const bf16x8*)&XT[tj*16 + r][k+kb];
      acc[tj] = MFMA16(a0,bb,acc[tj]);
    }
  }
  u16* Sp = S + (size_t)blk*8192;
  int g0 = wv*16 + (lane>>4)*4, p0 = lane&15;
  #pragma unroll
  for (int tj=0;tj<4;tj++)
    #pragma unroll
    for (int rr=0;rr<4;rr++)
      Sp[(g0 + rr)*64 + tj*16 + p0] = f2b(acc[tj][rr]);
}

// ---------------- K6: inter-chunk state scan (bf16 S, prefetched) ----------------
__global__ __launch_bounds__(256) void k_scan(const u16* __restrict__ S,
                                              const float* __restrict__ cumT,
                                              u16* __restrict__ Hp){
  int slice = blockIdx.x & 3;
  int bh = blockIdx.x >> 2;
  int b = bh >> 5, h = bh & 31;
  int e0 = slice*2048 + threadIdx.x*8;
  float c8[8];
  #pragma unroll
  for (int j=0;j<8;j++) c8[j] = 0.f;
  int blk0 = (b*16+0)*32 + h;
  uint4 sv = *(const uint4*)&S[(size_t)blk0*8192 + e0];
  float dl = expf(cumT[(size_t)blk0*128 + 127]);
  for (int c=0;c<NCHUNK;c++){
    int blkn = (b*16+c+1)*32 + h;
    uint4 nx; float dln = 0.f;
    if (c < NCHUNK-1){
      nx  = *(const uint4*)&S[(size_t)blkn*8192 + e0];
      dln = expf(cumT[(size_t)blkn*128 + 127]);
    }
    int blk = (b*16+c)*32 + h;
    const u16* sp = (const u16*)&sv;
    uint4 o; u16* op = (u16*)&o;
    #pragma unroll
    for (int j=0;j<8;j++) op[j] = f2b(c8[j]);
    *reinterpret_cast<uint4*>(&Hp[(size_t)blk*8192 + e0]) = o;
    #pragma unroll
    for (int j=0;j<8;j++) c8[j] = dl*c8[j] + b2f(sp[j]);
    sv = nx; dl = dln;
  }
}

// ---------------- K7: intra-chunk, 512 threads, C in regs, XT/HT staging overlapped ----------------
__global__ __launch_bounds__(512) void k_intra(const u16* __restrict__ Cm,
                                               const u16* __restrict__ Bm,
                                               const u16* __restrict__ xh,
                                               const u16* __restrict__ Hp,
                                               const float* __restrict__ dtT,
                                               const float* __restrict__ cumT,
                                               const float* __restrict__ Dskip,
                                               u16* __restrict__ yh){
  int blk = blockIdx.x;
  int h = blk & 31, bc = blk >> 5;
  __shared__ __align__(16) u16 Bl[128][136];
  __shared__ __align__(16) u16 XT[64][136];
  __shared__ __align__(16) u16 HT[64][136];
  __shared__ float cum[128], dtv[128];
  int tid = threadIdx.x;
  int lane = tid & 63, wv = tid >> 6;
  int r = lane & 15, kb = (lane>>4)*8;

  bf16x8 cfr[4];
  {
    const u16* cp = Cm + (size_t)(bc*128 + wv*16 + r)*4096 + h*128 + kb;
    #pragma unroll
    for (int ks=0;ks<4;ks++) cfr[ks] = *(const bf16x8*)(cp + ks*32);
  }

  if (tid < 128){ cum[tid] = cumT[(size_t)blk*128+tid]; dtv[tid] = dtT[(size_t)blk*128+tid]; }
  #pragma unroll
  for (int it=0; it<4; ++it){
    int rw = it*32 + (tid>>4);
    int g8 = (tid&15)*8;
    *(uint4*)&Bl[rw][g8] = *(const uint4*)&Bm[(size_t)(bc*128+rw)*4096 + h*128 + g8];
  }
  __syncthreads();

  uint2 xt[4], ht[4];
  #pragma unroll
  for (int it=0; it<4; ++it){
    int s  = it*32 + (tid>>4);
    int p4 = (tid&15)*4;
    xt[it] = *(const uint2*)&xh[(size_t)(bc*128+s)*DINNER + h*64 + p4];
    ht[it] = *(const uint2*)&Hp[(size_t)blk*8192 + (it*32 + (tid>>4))*64 + p4];
  }

  const int tjmax = wv;
  f32x4 p1[8];
  #pragma unroll
  for (int j=0;j<8;j++) p1[j] = (f32x4){0,0,0,0};
  #pragma unroll
  for (int ks=0;ks<4;ks++){
    bf16x8 a0 = cfr[ks];
    #pragma unroll
    for (int tj=0;tj<8;tj++){
      if (tj > tjmax) continue;
      bf16x8 bb = *(const bf16x8*)&Bl[tj*16 + r][ks*32+kb];
      p1[tj] = MFMA16(a0,bb,p1[tj]);
    }
  }
  #pragma unroll
  for (int it=0; it<4; ++it){
    int s  = it*32 + (tid>>4);
    int p4 = (tid&15)*4;
    const u16* pv = (const u16*)&xt[it];
    #pragma unroll
    for (int j=0;j<4;j++) XT[p4+j][s] = pv[j];
    const u16* ph = (const u16*)&ht[it];
    #pragma unroll
    for (int j=0;j<4;j++) HT[p4+j][it*32 + (tid>>4)] = ph[j];
  }
  __syncthreads();

  int row0 = wv*16 + (lane>>4)*4;
  #pragma unroll
  for (int tj=0;tj<8;tj++)
    #pragma unroll
    for (int rr=0;rr<4;rr++){
      int l = row0 + rr;
      int s = tj*16 + (lane&15);
      float v = p1[tj][rr];
      v = (s <= l) ? v * expf(cum[l]-cum[s]) * dtv[s] : 0.f;
      Bl[l][s] = f2b(v);
    }
  __syncthreads();

  f32x4 y[4];
  #pragma unroll
  for (int j=0;j<4;j++) y[j] = (f32x4){0,0,0,0};
  #pragma unroll
  for (int ks=0;ks<4;ks++){
    bf16x8 a0 = cfr[ks];
    #pragma unroll
    for (int tj=0;tj<4;tj++){
      bf16x8 bb = *(const bf16x8*)&HT[tj*16 + r][ks*32+kb];
      y[tj] = MFMA16(a0,bb,y[tj]);
    }
  }
  #pragma unroll
  for (int rr=0;rr<4;rr++){
    float e = expf(cum[row0 + rr]);
    #pragma unroll
    for (int tj=0;tj<4;tj++) y[tj][rr] *= e;
  }
  #pragma unroll
  for (int k=0;k<128;k+=32){
    bf16x8 a0 = *(const bf16x8*)&Bl[wv*16 + r][k+kb];
    #pragma unroll
    for (int tj=0;tj<4;tj++){
      bf16x8 bb = *(const bf16x8*)&XT[tj*16 + r][k+kb];
      y[tj] = MFMA16(a0,bb,y[tj]);
    }
  }
  float Dh = Dskip[h];
  #pragma unroll
  for (int tj=0;tj<4;tj++)
    #pragma unroll
    for (int rr=0;rr<4;rr++){
      int l = row0 + rr;
      int p = tj*16 + (lane&15);
      float xv = b2f(XT[p][l]);
      yh[(size_t)(bc*128 + l)*DINNER + h*64 + p] = f2b(y[tj][rr] + Dh*xv);
    }
}

// ---------------- K8: gated RMSNorm (vectorized 16B/lane) ----------------
__global__ __launch_bounds__(256) void k_gate(const u16* __restrict__ yh,
                                              const u16* __restrict__ zb,
                                              const float* __restrict__ gw,
                                              u16* __restrict__ out){
  int row = blockIdx.x, tid = threadIdx.x;
  const uint4 yv = reinterpret_cast<const uint4*>(yh + (size_t)row*DINNER)[tid];
  const uint4 zv = reinterpret_cast<const uint4*>(zb + (size_t)row*DINNER)[tid];
  const unsigned* yp = (const unsigned*)&yv;
  const unsigned* zp = (const unsigned*)&zv;
  float t[8]; float ss = 0.f;
  #pragma unroll
  for (int i=0;i<4;i++){
    float y0 = b2f((u16)yp[i]), y1 = b2f((u16)(yp[i]>>16));
    float z0 = b2f((u16)zp[i]), z1 = b2f((u16)(zp[i]>>16));
    float v0 = y0 * (z0 / (1.f + expf(-z0)));
    float v1 = y1 * (z1 / (1.f + expf(-z1)));
    t[2*i] = v0; t[2*i+1] = v1; ss += v0*v0 + v1*v1;
  }
  #pragma unroll
  for (int off=32; off>0; off>>=1) ss += __shfl_down(ss, off, 64);
  __shared__ float red[4];
  if ((tid&63)==0) red[tid>>6] = ss;
  __syncthreads();
  float tot = red[0]+red[1]+red[2]+red[3];
  float g = rsqrtf(tot/(float)DINNER + 1e-5f);
  const float4 g0 = reinterpret_cast<const float4*>(gw)[tid*2];
  const float4 g1 = reinterpret_cast<const float4*>(gw)[tid*2+1];
  uint4 o;
  unsigned* op = (unsigned*)&o;
  float gg[8] = {g0.x,g0.y,g0.z,g0.w,g1.x,g1.y,g1.z,g1.w};
  #pragma unroll
  for (int i=0;i<4;i++)
    op[i] = (unsigned)f2b(t[2*i]*gg[2*i]*g) | ((unsigned)f2b(t[2*i+1]*gg[2*i+1]*g)<<16);
  reinterpret_cast<uint4*>(out + (size_t)row*DINNER)[tid] = o;
}

// ======== GEMM2: 128x128 tile, BK=64, 2-slot ring (64 KB), counted vmcnt ========
// Epilogue via LDS f32 transpose (exactly 64 KB) -> float4 xres loads + float4 stores.
__global__ __launch_bounds__(256) void k_gemm2_64(const u16* __restrict__ A,
                                                  const u16* __restrict__ W,
                                                  const float* __restrict__ xres,
                                                  float* __restrict__ out){
  __shared__ __align__(16) u16 lds[2*16384];
  const int tid  = threadIdx.x;
  const int lane = tid & 63, wv = tid >> 6;
  const int wr = wv >> 1, wc = wv & 1;
  const int NWG = 8*32, Q = NWG/8;
  int swz = (blockIdx.x & 7)*Q + (blockIdx.x >> 3);
  int tm = swz / 8, tn = swz % 8;
  int m0 = tm*128, n0 = tn*128;
  const int K = DINNER;

  const int srow = tid >> 3;
  const int sslot = ((tid&7) ^ ((tid>>3)&7))*8;
  const u16* aSrc = A + (size_t)(m0 + srow)*K + sslot;
  const u16* bSrc = W + (size_t)(n0 + srow)*K + sslot;
  const int ldsu = wv*512;

  const int rr = lane & 15, gq = lane >> 4;

  f32x4 acc[4][4];
  #pragma unroll
  for (int i=0;i<4;i++)
    #pragma unroll
    for (int j=0;j<4;j++) acc[i][j] = (f32x4){0,0,0,0};

  auto STAGE = [&](int kt){
    u16* base = lds + (kt&1)*16384;
    #pragma unroll
    for (int j=0;j<4;j++)
      gload_lds16(aSrc + (size_t)(j*32)*K + kt*64, base + j*2048 + ldsu);
    #pragma unroll
    for (int j=0;j<4;j++)
      gload_lds16(bSrc + (size_t)(j*32)*K + kt*64, base + 8192 + j*2048 + ldsu);
  };
  auto KSTEP = [&](int kt, bool stg){
    const u16* bufA = lds + (kt&1)*16384;
    const u16* bufB = bufA + 8192;
    bf16x8 af[4][2], bw[4][2];
    #pragma unroll
    for (int t=0;t<4;t++){
      #pragma unroll
      for (int ks=0;ks<2;ks++){
        int sa = (ks*4 + gq) ^ (rr & 7);
        af[t][ks] = *(const bf16x8*)&bufA[(wr*64 + t*16 + rr)*64 + sa*8];
        bw[t][ks] = *(const bf16x8*)&bufB[(wc*64 + t*16 + rr)*64 + sa*8];
      }
    }
    asm volatile("s_waitcnt lgkmcnt(0)" ::: "memory");
    __builtin_amdgcn_s_barrier();
    if (stg) STAGE(kt+2);
    __builtin_amdgcn_s_setprio(1);
    #pragma unroll
    for (int ti=0;ti<4;ti++)
      #pragma unroll
      for (int tj=0;tj<4;tj++){
        acc[ti][tj] = MFMA16(af[ti][0], bw[tj][0], acc[ti][tj]);
        acc[ti][tj] = MFMA16(af[ti][1], bw[tj][1], acc[ti][tj]);
      }
    __builtin_amdgcn_s_setprio(0);
  };

  STAGE(0); STAGE(1);
  asm volatile("s_waitcnt vmcnt(8)" ::: "memory");
  __builtin_amdgcn_s_barrier();
  __builtin_amdgcn_sched_barrier(0);
  const int NT = K/64;
  for (int kt = 0; kt < NT-2; ++kt){
    KSTEP(kt, true);
    asm volatile("s_waitcnt vmcnt(8)" ::: "memory");
    __builtin_amdgcn_s_barrier();
    __builtin_amdgcn_sched_barrier(0);
  }
  KSTEP(NT-2, false);
  asm volatile("s_waitcnt vmcnt(0)" ::: "memory");
  __builtin_amdgcn_s_barrier();
  __builtin_amdgcn_sched_barrier(0);
  KSTEP(NT-1, false);

  // epilogue: acc -> LDS (f32, swizzle col^((row&7)<<2)) -> float4 + residual
  float* fl = (float*)lds;
  #pragma unroll
  for (int ti=0;ti<4;ti++)
    #pragma unroll
    for (int tj=0;tj<4;tj++)
      #pragma unroll
      for (int q=0;q<4;q++){
        int rl = wr*64 + ti*16 + (lane>>4)*4 + q;
        int cl = wc*64 + tj*16 + (lane&15);
        fl[rl*128 + (cl ^ ((rl&7)<<2))] = acc[ti][tj][q];
      }
  __syncthreads();
  {
    int r  = tid & 127;
    int hb = (tid >> 7) * 64;
    const float* xr = xres + (size_t)(m0 + r)*DMODEL + n0 + hb;
    float* orow = out + (size_t)(m0 + r)*DMODEL + n0 + hb;
    #pragma unroll
    for (int i=0;i<16;i++){
      int c = hb + i*4;
      float4 v = *(const float4*)&fl[r*128 + (c ^ ((r&7)<<2))];
      float4 xv = *(const float4*)&xr[i*4];
      v.x += xv.x; v.y += xv.y; v.z += xv.z; v.w += xv.w;
      *(float4*)&orow[i*4] = v;
    }
  }
}

extern "C" void kernel_launch(void* const* d_in, const int* in_sizes, int n_in,
                              void* d_out, int out_size, void* d_ws, size_t ws_size,
                              hipStream_t stream) {
  (void)in_sizes; (void)n_in; (void)out_size; (void)ws_size;
  const float* x         = (const float*)d_in[0];
  const float* norm_w    = (const float*)d_in[1];
  const float* in_proj_w = (const float*)d_in[2];
  const float* conv_w    = (const float*)d_in[3];
  const float* conv_b    = (const float*)d_in[4];
  const float* dt_bias   = (const float*)d_in[5];
  const float* A_log     = (const float*)d_in[6];
  const float* D_skip    = (const float*)d_in[7];
  const float* gnorm_w   = (const float*)d_in[8];
  const float* out_proj_w= (const float*)d_in[9];
  float* out = (float*)d_out;

  char* ws = (char*)d_ws;
  size_t off = 0;
  auto alloc = [&](size_t bytes)->char*{
    char* p = ws + off; off = (off + bytes + 255) & ~(size_t)255; return p;
  };
  u16*   W2    = (u16*)  alloc((size_t)DMODEL*DINNER*2);
  u16*   zb    = (u16*)  alloc((size_t)NROWS*DINNER*2);
  float* dtraw = (float*)alloc((size_t)NROWS*NHEADS*4);
  float* dtT   = (float*)alloc((size_t)1024*128*4);
  float* cumT  = (float*)alloc((size_t)1024*128*4);
  u16*   xhb   = (u16*)  alloc((size_t)NROWS*DINNER*2);
  u16*   Bmb   = (u16*)  alloc((size_t)NROWS*4096*2);
  u16*   Cmb   = (u16*)  alloc((size_t)NROWS*4096*2);
  char*  R1    = alloc((size_t)NROWS*DXBC*2);
  u16*   xbcr  = (u16*)R1;
  u16*   S     = (u16*)R1;
  u16*   Hp    = (u16*)(R1 + (size_t)1024*8192*4);
  u16*   yh    = (u16*)R1;
  char*  R2    = alloc((size_t)DPROJ*DMODEL*2 + (size_t)NROWS*DMODEL*2);
  u16*   W1    = (u16*)R2;
  u16*   u_bf  = (u16*)(R2 + (size_t)DPROJ*DMODEL*2);
  u16*   gated = (u16*)R2;

  k_prep<<<2048+NROWS,256,0,stream>>>(in_proj_w, W1, DPROJ*DMODEL,
                                      out_proj_w, W2, DMODEL*DINNER,
                                      x, norm_w, u_bf);
  k_gemm_dt<<<NROWS/32,256,0,stream>>>(u_bf, W1, dtraw);
  k_gemm1_8p<<<768,512,0,stream>>>(u_bf, W1, zb, xbcr);
  k_convdt<<<1280+512,256,0,stream>>>(xbcr, conv_w, conv_b, xhb, Bmb, Cmb,
                                      dtraw, dt_bias, A_log, dtT, cumT);
  k_states<<<1024,512,0,stream>>>(Bmb, xhb, dtT, cumT, S);
  k_scan<<<256,256,0,stream>>>(S, cumT, Hp);
  k_intra<<<1024,512,0,stream>>>(Cmb, Bmb, xhb, Hp, dtT, cumT, D_skip, yh);
  k_gate<<<NROWS,256,0,stream>>>(yh, zb, gnorm_w, gated);
  k_gemm2_64<<<8*32,256,0,stream>>>(gated, W2, x, out);
}

// Round 19
// 287.627 us; speedup vs baseline: 1.0995x; 1.0995x over previous
//
#include <hip/hip_runtime.h>

typedef unsigned short u16;
typedef __attribute__((ext_vector_type(8))) short bf16x8;
typedef __attribute__((ext_vector_type(4))) float f32x4;

#define MFMA16(a,b,c) __builtin_amdgcn_mfma_f32_16x16x32_bf16(a,b,c,0,0,0)

// ---- constants ----
#define DMODEL   1024
#define DINNER   2048
#define NHEADS   32
#define HEADDIM  64
#define GDIM     128
#define DXBC     10240
#define DPROJ    12320
#define CHUNK_L  128
#define NCHUNK   16
#define NROWS    4096

__device__ __forceinline__ float b2f(u16 u){ return __uint_as_float(((unsigned)u)<<16); }
__device__ __forceinline__ u16 f2b(float f){
  unsigned u = __float_as_uint(f);
  u += 0x7fffu + ((u>>16)&1u);
  return (u16)(u>>16);
}

__device__ __forceinline__ void gload_lds16(const void* g, void* l){
  __builtin_amdgcn_global_load_lds(
      (const __attribute__((address_space(1))) unsigned int*)g,
      (__attribute__((address_space(3))) unsigned int*)l, 16, 0, 0);
}

// ---------------- K0: prologue merge — weight f2b (blocks <2048) + input RMSNorm (>=2048) ----------------
__global__ __launch_bounds__(256) void k_prep(const float* __restrict__ s1, u16* __restrict__ d1, int n1,
                                              const float* __restrict__ s2, u16* __restrict__ d2, int n2,
                                              const float* __restrict__ x, const float* __restrict__ w,
                                              u16* __restrict__ u){
  __shared__ float red[4];
  if (blockIdx.x < 2048){
    int i = blockIdx.x*256 + threadIdx.x;
    int stride = 2048*256;
    int t1 = n1 >> 2, t2 = n2 >> 2;
    for (int j=i; j<t1+t2; j+=stride){
      const float4* sp; uint2* dp; int idx;
      if (j < t1){ sp = (const float4*)s1; dp = (uint2*)d1; idx = j; }
      else       { sp = (const float4*)s2; dp = (uint2*)d2; idx = j - t1; }
      float4 v = sp[idx];
      uint2 o;
      o.x = (unsigned)f2b(v.x) | ((unsigned)f2b(v.y)<<16);
      o.y = (unsigned)f2b(v.z) | ((unsigned)f2b(v.w)<<16);
      dp[idx] = o;
    }
  } else {
    int row = blockIdx.x - 2048, tid = threadIdx.x;
    float4 v = reinterpret_cast<const float4*>(x + (size_t)row*DMODEL)[tid];
    float ss = v.x*v.x + v.y*v.y + v.z*v.z + v.w*v.w;
    #pragma unroll
    for (int off=32; off>0; off>>=1) ss += __shfl_down(ss, off, 64);
    if ((tid&63)==0) red[tid>>6] = ss;
    __syncthreads();
    float tot = red[0]+red[1]+red[2]+red[3];
    float sc = rsqrtf(tot/(float)DMODEL + 1e-5f);
    float4 wv = reinterpret_cast<const float4*>(w)[tid];
    uint2 o;
    o.x = (unsigned)f2b(v.x*wv.x*sc) | ((unsigned)f2b(v.y*wv.y*sc)<<16);
    o.y = (unsigned)f2b(v.z*wv.z*sc) | ((unsigned)f2b(v.w*wv.w*sc)<<16);
    reinterpret_cast<uint2*>(u + (size_t)row*DMODEL)[tid] = o;
  }
}

// ======== GEMM1: 256x256 tile, BK=64, 8 waves, 4-phase, counted vmcnt ========
__global__ __launch_bounds__(512) void k_gemm1_8p(const u16* __restrict__ A,
                                                  const u16* __restrict__ W,
                                                  u16* __restrict__ zb,
                                                  u16* __restrict__ xbc){
  __shared__ __align__(16) u16 lds[65536];     // 128 KB
  const int tid  = threadIdx.x;
  const int lane = tid & 63, w = tid >> 6;
  const int wr = w >> 2, wc = w & 3;
  int bid = blockIdx.x;
  int xcd = bid & 7, g = bid >> 3;
  int st  = xcd*6 + (g >> 4);
  int wi  = g & 15;
  int tm  = (st/12)*4 + (wi>>2);
  int tn  = (st%12)*4 + (wi&3);
  const int m0 = tm*256, n0 = tn*256;

  const int srow = w*8 + (lane>>3);
  const int scol = ((lane&7) ^ ((lane>>3)&7))*8;
  const u16* aS = A + (size_t)(m0 + srow)*DMODEL + scol;
  const u16* bS = W + (size_t)(n0 + srow)*DMODEL + scol;
  const int ldsw = w*512;

  const int rr = lane & 15, gq = lane >> 4;

  f32x4 acc[8][4];
  #pragma unroll
  for (int i=0;i<8;i++)
    #pragma unroll
    for (int j=0;j<4;j++) acc[i][j] = (f32x4){0,0,0,0};

  auto SU_A = [&](int kt, int j){
    gload_lds16(aS + (size_t)(j*64)*DMODEL + kt*64,
                lds + (kt&1)*32768 + j*4096 + ldsw);
  };
  auto SU_B = [&](int kt, int j){
    gload_lds16(bS + (size_t)(j*64)*DMODEL + kt*64,
                lds + (kt&1)*32768 + 16384 + j*4096 + ldsw);
  };

  SU_A(0,0); SU_A(0,2); SU_B(0,0); SU_B(0,2); SU_B(0,1); SU_B(0,3); SU_A(0,1); SU_A(0,3);
  asm volatile("s_waitcnt vmcnt(2)" ::: "memory");
  __builtin_amdgcn_s_barrier();
  __builtin_amdgcn_sched_barrier(0);

  for (int kt = 0; kt < 16; ++kt){
    const u16* bufA = lds + (kt&1)*32768;
    const u16* bufB = bufA + 16384;
    const bool stg = (kt < 15);
    bf16x8 af[4][2], bw0[2][2], bw1[2][2];

    auto RDA = [&](int ti, int ks)->bf16x8{
      int r = wr*128 + ti*16 + rr;
      int s = (ks*4 + gq) ^ (rr & 7);
      return *(const bf16x8*)&bufA[r*64 + s*8];
    };
    auto RDB = [&](int tj, int ks)->bf16x8{
      int r = wc*64 + tj*16 + rr;
      int s = (ks*4 + gq) ^ (rr & 7);
      return *(const bf16x8*)&bufB[r*64 + s*8];
    };

    // phase 1
    #pragma unroll
    for (int ti=0;ti<4;ti++){ af[ti][0]=RDA(ti,0); af[ti][1]=RDA(ti,1); }
    #pragma unroll
    for (int tj=0;tj<2;tj++){ bw0[tj][0]=RDB(tj,0); bw0[tj][1]=RDB(tj,1); }
    if (stg){ SU_A(kt+1,0); SU_A(kt+1,2); }
    __builtin_amdgcn_s_barrier();
    asm volatile("s_waitcnt lgkmcnt(0)" ::: "memory");
    __builtin_amdgcn_sched_barrier(0);
    __builtin_amdgcn_s_setprio(1);
    #pragma unroll
    for (int ti=0;ti<4;ti++)
      #pragma unroll
      for (int tj=0;tj<2;tj++){
        acc[ti][tj] = MFMA16(af[ti][0], bw0[tj][0], acc[ti][tj]);
        acc[ti][tj] = MFMA16(af[ti][1], bw0[tj][1], acc[ti][tj]);
      }
    __builtin_amdgcn_s_setprio(0);
    __builtin_amdgcn_s_barrier();

    // phase 2
    #pragma unroll
    for (int tj=0;tj<2;tj++){ bw1[tj][0]=RDB(tj+2,0); bw1[tj][1]=RDB(tj+2,1); }
    if (stg){ SU_B(kt+1,0); SU_B(kt+1,2); }
    __builtin_amdgcn_s_barrier();
    asm volatile("s_waitcnt lgkmcnt(0)" ::: "memory");
    __builtin_amdgcn_sched_barrier(0);
    __builtin_amdgcn_s_setprio(1);
    #pragma unroll
    for (int ti=0;ti<4;ti++)
      #pragma unroll
      for (int tj=0;tj<2;tj++){
        acc[ti][tj+2] = MFMA16(af[ti][0], bw1[tj][0], acc[ti][tj+2]);
        acc[ti][tj+2] = MFMA16(af[ti][1], bw1[tj][1], acc[ti][tj+2]);
      }
    __builtin_amdgcn_s_setprio(0);
    if (stg) asm volatile("s_waitcnt vmcnt(4)" ::: "memory");
    else     asm volatile("s_waitcnt vmcnt(0)" ::: "memory");
    __builtin_amdgcn_s_barrier();

    // phase 3
    #pragma unroll
    for (int ti=0;ti<4;ti++){ af[ti][0]=RDA(ti+4,0); af[ti][1]=RDA(ti+4,1); }
    if (stg){ SU_B(kt+1,1); SU_B(kt+1,3); }
    __builtin_amdgcn_s_barrier();
    asm volatile("s_waitcnt lgkmcnt(0)" ::: "memory");
    __builtin_amdgcn_sched_barrier(0);
    __builtin_amdgcn_s_setprio(1);
    #pragma unroll
    for (int ti=0;ti<4;ti++)
      #pragma unroll
      for (int tj=0;tj<2;tj++){
        acc[4+ti][tj] = MFMA16(af[ti][0], bw0[tj][0], acc[4+ti][tj]);
        acc[4+ti][tj] = MFMA16(af[ti][1], bw0[tj][1], acc[4+ti][tj]);
      }
    __builtin_amdgcn_s_setprio(0);
    __builtin_amdgcn_s_barrier();

    // phase 4
    if (stg){ SU_A(kt+1,1); SU_A(kt+1,3); }
    __builtin_amdgcn_s_barrier();
    __builtin_amdgcn_sched_barrier(0);
    __builtin_amdgcn_s_setprio(1);
    #pragma unroll
    for (int ti=0;ti<4;ti++)
      #pragma unroll
      for (int tj=0;tj<2;tj++){
        acc[4+ti][tj+2] = MFMA16(af[ti][0], bw1[tj][0], acc[4+ti][tj+2]);
        acc[4+ti][tj+2] = MFMA16(af[ti][1], bw1[tj][1], acc[4+ti][tj+2]);
      }
    __builtin_amdgcn_s_setprio(0);
    if (stg){
      asm volatile("s_waitcnt vmcnt(2)" ::: "memory");
      __builtin_amdgcn_s_barrier();
      __builtin_amdgcn_sched_barrier(0);
    }
  }

  const int row0 = m0 + wr*128 + (lane>>4)*4;
  const int colb = wc*64 + (lane&15);
  if (tn >= 8){
    const int cb = n0 - DINNER;
    #pragma unroll
    for (int ti=0;ti<8;ti++)
      #pragma unroll
      for (int tj=0;tj<4;tj++)
        #pragma unroll
        for (int q=0;q<4;q++)
          xbc[(size_t)(row0 + ti*16 + q)*DXBC + cb + colb + tj*16] = f2b(acc[ti][tj][q]);
  } else {
    #pragma unroll
    for (int ti=0;ti<8;ti++)
      #pragma unroll
      for (int tj=0;tj<4;tj++)
        #pragma unroll
        for (int q=0;q<4;q++)
          zb[(size_t)(row0 + ti*16 + q)*DINNER + n0 + colb + tj*16] = f2b(acc[ti][tj][q]);
  }
}

// ---------------- K2b: GEMM1 dt strip (cols 12288..12319), K-split over waves ----------------
__global__ __launch_bounds__(256) void k_gemm_dt(const u16* __restrict__ A,
                                                 const u16* __restrict__ W,
                                                 float* __restrict__ dtraw){
  const int lane = threadIdx.x & 63, wv = threadIdx.x >> 6;
  const int m0 = blockIdx.x*32;
  const int n0 = DINNER + DXBC;   // 12288
  const int r  = lane & 15;
  const int kb = (lane>>4)*8;
  const int k0 = wv*256;
  const u16* a0p = A + (size_t)(m0 + r)*DMODEL + k0 + kb;
  const u16* a1p = a0p + 16*DMODEL;
  const u16* b0p = W + (size_t)(n0 + r)*DMODEL + k0 + kb;
  const u16* b1p = b0p + 16*DMODEL;
  f32x4 acc00={0,0,0,0}, acc01={0,0,0,0}, acc10={0,0,0,0}, acc11={0,0,0,0};
  #pragma unroll
  for (int k=0;k<256;k+=32){
    bf16x8 a0 = *(const bf16x8*)(a0p + k);
    bf16x8 a1 = *(const bf16x8*)(a1p + k);
    bf16x8 b0 = *(const bf16x8*)(b0p + k);
    bf16x8 b1 = *(const bf16x8*)(b1p + k);
    acc00 = MFMA16(a0,b0,acc00);
    acc01 = MFMA16(a0,b1,acc01);
    acc10 = MFMA16(a1,b0,acc10);
    acc11 = MFMA16(a1,b1,acc11);
  }
  __shared__ float part[4][1024];
  int rowb = (lane>>4)*4, col = lane&15;
  #pragma unroll
  for (int rr=0; rr<4; rr++){
    part[wv][(rowb+rr)*32 + col]         = acc00[rr];
    part[wv][(rowb+rr)*32 + col+16]      = acc01[rr];
    part[wv][(rowb+16+rr)*32 + col]      = acc10[rr];
    part[wv][(rowb+16+rr)*32 + col+16]   = acc11[rr];
  }
  __syncthreads();
  int idx = threadIdx.x*4;
  #pragma unroll
  for (int q=0;q<4;q++){
    int i = idx+q;
    dtraw[(size_t)m0*NHEADS + i] = part[0][i]+part[1][i]+part[2][i]+part[3][i];
  }
}

// ---------------- K3+K4 merged launch: conv (blocks <2560) + dtscan (>=2560) ----------------
__global__ __launch_bounds__(256) void k_convdt(const u16* __restrict__ xbc,
                                                const float* __restrict__ cw,
                                                const float* __restrict__ cb,
                                                u16* __restrict__ xh,
                                                u16* __restrict__ Bm,
                                                u16* __restrict__ Cm,
                                                const float* __restrict__ dtraw,
                                                const float* __restrict__ dt_bias,
                                                const float* __restrict__ A_log,
                                                float* __restrict__ dtT,
                                                float* __restrict__ cumT){
  __shared__ float lds2[2][128];
  int tid = threadIdx.x;
  if (blockIdx.x < 2560){
    // conv: 4 channels/thread, 16 rows/thread rolling window
    int cblk = blockIdx.x;
    int cx = cblk % 10, ry = cblk / 10;
    int c0 = (cx*256 + tid)*4;
    int row0 = ry*16;
    int l0 = row0 & 2047;
    float4 w4[4]; float cbv[4];
    #pragma unroll
    for (int j=0;j<4;j++){ w4[j] = reinterpret_cast<const float4*>(cw)[c0+j]; cbv[j] = cb[c0+j]; }
    float p3[4]={0,0,0,0}, p2[4]={0,0,0,0}, p1[4]={0,0,0,0};
    auto loadquad = [&](int rw, float q[4]){
      uint2 v = *(const uint2*)&xbc[(size_t)rw*DXBC + c0];
      const u16* pv = (const u16*)&v;
      #pragma unroll
      for (int j=0;j<4;j++) q[j] = b2f(pv[j]);
    };
    if (l0 >= 3){ loadquad(row0-3,p3); loadquad(row0-2,p2); loadquad(row0-1,p1); }
    #pragma unroll
    for (int i=0;i<16;i++){
      float cur[4]; loadquad(row0+i, cur);
      float o[4];
      #pragma unroll
      for (int j=0;j<4;j++){
        float s = cbv[j] + p3[j]*w4[j].x + p2[j]*w4[j].y + p1[j]*w4[j].z + cur[j]*w4[j].w;
        o[j] = s/(1.f+expf(-s));
      }
      uint2 ov;
      ov.x = (unsigned)f2b(o[0]) | ((unsigned)f2b(o[1])<<16);
      ov.y = (unsigned)f2b(o[2]) | ((unsigned)f2b(o[3])<<16);
      int rw = row0 + i;
      if (c0 < DINNER)            *(uint2*)&xh[(size_t)rw*DINNER + c0] = ov;
      else if (c0 < DINNER+4096)  *(uint2*)&Bm[(size_t)rw*4096 + (c0-DINNER)] = ov;
      else                        *(uint2*)&Cm[(size_t)rw*4096 + (c0-DINNER-4096)] = ov;
      #pragma unroll
      for (int j=0;j<4;j++){ p3[j]=p2[j]; p2[j]=p1[j]; p1[j]=cur[j]; }
    }
  } else {
    // dtscan: two (bc,h) scans per block (128 threads each)
    int half = tid >> 7;
    int blk  = (blockIdx.x - 2560)*2 + half;   // 0..1023
    int h  = blk & 31;
    int bc = blk >> 5;
    int s  = tid & 127;
    int row = bc*128 + s;
    float xv = dtraw[(size_t)row*NHEADS + h] + dt_bias[h];
    float dt = (xv > 20.f) ? xv : log1pf(expf(xv));
    float a  = dt * (-expf(A_log[h]));
    lds2[half][s] = a; __syncthreads();
    #pragma unroll
    for (int off=1; off<128; off<<=1){
      float t = (s>=off) ? lds2[half][s-off] : 0.f;
      __syncthreads();
      lds2[half][s] += t;
      __syncthreads();
    }
    dtT[(size_t)blk*128 + s]  = dt;
    cumT[(size_t)blk*128 + s] = lds2[half][s];
  }
}

// ---------------- K5: chunk states S[g][p] (bf16), 512 threads, 8 waves ----------------
__global__ __launch_bounds__(512) void k_states(const u16* __restrict__ Bm,
                                                const u16* __restrict__ xh,
                                                const float* __restrict__ dtT,
                                                const float* __restrict__ cumT,
                                                u16* __restrict__ S){
  int blk = blockIdx.x;
  int h = blk & 31, bc = blk >> 5;
  __shared__ __align__(16) u16 Bw[128][136];
  __shared__ __align__(16) u16 XT[64][136];
  __shared__ float cum[128], dtv[128];
  int tid = threadIdx.x;
  if (tid < 128){ cum[tid] = cumT[(size_t)blk*128+tid]; dtv[tid] = dtT[(size_t)blk*128+tid]; }
  __syncthreads();
  float clast = cum[127];
  #pragma unroll
  for (int it=0; it<4; ++it){
    int s  = it*32 + (tid>>4);
    int g8 = (tid&15)*8;
    uint4 v = *(const uint4*)&Bm[(size_t)(bc*128+s)*4096 + h*128 + g8];
    float w = expf(clast - cum[s]) * dtv[s];
    const u16* pv = (const u16*)&v;
    #pragma unroll
    for (int j=0;j<8;j++) Bw[g8+j][s] = f2b(b2f(pv[j]) * w);
  }
  #pragma unroll
  for (int it=0; it<4; ++it){
    int s  = it*32 + (tid>>4);
    int p4 = (tid&15)*4;
    uint2 v = *(const uint2*)&xh[(size_t)(bc*128+s)*DINNER + h*64 + p4];
    const u16* pv = (const u16*)&v;
    #pragma unroll
    for (int j=0;j<4;j++) XT[p4+j][s] = pv[j];
  }
  __syncthreads();
  int lane = tid & 63, wv = tid >> 6;
  int r = lane & 15, kb = (lane>>4)*8;
  f32x4 acc[4];
  #pragma unroll
  for (int j=0;j<4;j++) acc[j] = (f32x4){0,0,0,0};
  #pragma unroll
  for (int k=0;k<128;k+=32){
    bf16x8 a0 = *(const bf16x8*)&Bw[wv*16 + r][k+kb];
    #pragma unroll
    for (int tj=0;tj<4;tj++){
      bf16x8 bb = *(const bf16x8*)&XT[tj*16 + r][k+kb];
      acc[tj] = MFMA16(a0,bb,acc[tj]);
    }
  }
  u16* Sp = S + (size_t)blk*8192;
  int g0 = wv*16 + (lane>>4)*4, p0 = lane&15;
  #pragma unroll
  for (int tj=0;tj<4;tj++)
    #pragma unroll
    for (int rr=0;rr<4;rr++)
      Sp[(g0 + rr)*64 + tj*16 + p0] = f2b(acc[tj][rr]);
}

// ---------------- K6: inter-chunk state scan (bf16 S, prefetched) ----------------
__global__ __launch_bounds__(256) void k_scan(const u16* __restrict__ S,
                                              const float* __restrict__ cumT,
                                              u16* __restrict__ Hp){
  int slice = blockIdx.x & 3;
  int bh = blockIdx.x >> 2;
  int b = bh >> 5, h = bh & 31;
  int e0 = slice*2048 + threadIdx.x*8;
  float c8[8];
  #pragma unroll
  for (int j=0;j<8;j++) c8[j] = 0.f;
  int blk0 = (b*16+0)*32 + h;
  uint4 sv = *(const uint4*)&S[(size_t)blk0*8192 + e0];
  float dl = expf(cumT[(size_t)blk0*128 + 127]);
  for (int c=0;c<NCHUNK;c++){
    int blkn = (b*16+c+1)*32 + h;
    uint4 nx; float dln = 0.f;
    if (c < NCHUNK-1){
      nx  = *(const uint4*)&S[(size_t)blkn*8192 + e0];
      dln = expf(cumT[(size_t)blkn*128 + 127]);
    }
    int blk = (b*16+c)*32 + h;
    const u16* sp = (const u16*)&sv;
    uint4 o; u16* op = (u16*)&o;
    #pragma unroll
    for (int j=0;j<8;j++) op[j] = f2b(c8[j]);
    *reinterpret_cast<uint4*>(&Hp[(size_t)blk*8192 + e0]) = o;
    #pragma unroll
    for (int j=0;j<8;j++) c8[j] = dl*c8[j] + b2f(sp[j]);
    sv = nx; dl = dln;
  }
}

// ---------------- K7: intra-chunk, 512 threads, C in regs, XT/HT staging overlapped ----------------
__global__ __launch_bounds__(512) void k_intra(const u16* __restrict__ Cm,
                                               const u16* __restrict__ Bm,
                                               const u16* __restrict__ xh,
                                               const u16* __restrict__ Hp,
                                               const float* __restrict__ dtT,
                                               const float* __restrict__ cumT,
                                               const float* __restrict__ Dskip,
                                               u16* __restrict__ yh){
  int blk = blockIdx.x;
  int h = blk & 31, bc = blk >> 5;
  __shared__ __align__(16) u16 Bl[128][136];
  __shared__ __align__(16) u16 XT[64][136];
  __shared__ __align__(16) u16 HT[64][136];
  __shared__ float cum[128], dtv[128];
  int tid = threadIdx.x;
  int lane = tid & 63, wv = tid >> 6;
  int r = lane & 15, kb = (lane>>4)*8;

  bf16x8 cfr[4];
  {
    const u16* cp = Cm + (size_t)(bc*128 + wv*16 + r)*4096 + h*128 + kb;
    #pragma unroll
    for (int ks=0;ks<4;ks++) cfr[ks] = *(const bf16x8*)(cp + ks*32);
  }

  if (tid < 128){ cum[tid] = cumT[(size_t)blk*128+tid]; dtv[tid] = dtT[(size_t)blk*128+tid]; }
  #pragma unroll
  for (int it=0; it<4; ++it){
    int rw = it*32 + (tid>>4);
    int g8 = (tid&15)*8;
    *(uint4*)&Bl[rw][g8] = *(const uint4*)&Bm[(size_t)(bc*128+rw)*4096 + h*128 + g8];
  }
  __syncthreads();

  uint2 xt[4], ht[4];
  #pragma unroll
  for (int it=0; it<4; ++it){
    int s  = it*32 + (tid>>4);
    int p4 = (tid&15)*4;
    xt[it] = *(const uint2*)&xh[(size_t)(bc*128+s)*DINNER + h*64 + p4];
    ht[it] = *(const uint2*)&Hp[(size_t)blk*8192 + (it*32 + (tid>>4))*64 + p4];
  }

  const int tjmax = wv;
  f32x4 p1[8];
  #pragma unroll
  for (int j=0;j<8;j++) p1[j] = (f32x4){0,0,0,0};
  #pragma unroll
  for (int ks=0;ks<4;ks++){
    bf16x8 a0 = cfr[ks];
    #pragma unroll
    for (int tj=0;tj<8;tj++){
      if (tj > tjmax) continue;
      bf16x8 bb = *(const bf16x8*)&Bl[tj*16 + r][ks*32+kb];
      p1[tj] = MFMA16(a0,bb,p1[tj]);
    }
  }
  #pragma unroll
  for (int it=0; it<4; ++it){
    int s  = it*32 + (tid>>4);
    int p4 = (tid&15)*4;
    const u16* pv = (const u16*)&xt[it];
    #pragma unroll
    for (int j=0;j<4;j++) XT[p4+j][s] = pv[j];
    const u16* ph = (const u16*)&ht[it];
    #pragma unroll
    for (int j=0;j<4;j++) HT[p4+j][it*32 + (tid>>4)] = ph[j];
  }
  __syncthreads();

  int row0 = wv*16 + (lane>>4)*4;
  #pragma unroll
  for (int tj=0;tj<8;tj++)
    #pragma unroll
    for (int rr=0;rr<4;rr++){
      int l = row0 + rr;
      int s = tj*16 + (lane&15);
      float v = p1[tj][rr];
      v = (s <= l) ? v * expf(cum[l]-cum[s]) * dtv[s] : 0.f;
      Bl[l][s] = f2b(v);
    }
  __syncthreads();

  f32x4 y[4];
  #pragma unroll
  for (int j=0;j<4;j++) y[j] = (f32x4){0,0,0,0};
  #pragma unroll
  for (int ks=0;ks<4;ks++){
    bf16x8 a0 = cfr[ks];
    #pragma unroll
    for (int tj=0;tj<4;tj++){
      bf16x8 bb = *(const bf16x8*)&HT[tj*16 + r][ks*32+kb];
      y[tj] = MFMA16(a0,bb,y[tj]);
    }
  }
  #pragma unroll
  for (int rr=0;rr<4;rr++){
    float e = expf(cum[row0 + rr]);
    #pragma unroll
    for (int tj=0;tj<4;tj++) y[tj][rr] *= e;
  }
  #pragma unroll
  for (int k=0;k<128;k+=32){
    bf16x8 a0 = *(const bf16x8*)&Bl[wv*16 + r][k+kb];
    #pragma unroll
    for (int tj=0;tj<4;tj++){
      bf16x8 bb = *(const bf16x8*)&XT[tj*16 + r][k+kb];
      y[tj] = MFMA16(a0,bb,y[tj]);
    }
  }
  float Dh = Dskip[h];
  #pragma unroll
  for (int tj=0;tj<4;tj++)
    #pragma unroll
    for (int rr=0;rr<4;rr++){
      int l = row0 + rr;
      int p = tj*16 + (lane&15);
      float xv = b2f(XT[p][l]);
      yh[(size_t)(bc*128 + l)*DINNER + h*64 + p] = f2b(y[tj][rr] + Dh*xv);
    }
}

// ---------------- K8: gated RMSNorm (vectorized 16B/lane) ----------------
__global__ __launch_bounds__(256) void k_gate(const u16* __restrict__ yh,
                                              const u16* __restrict__ zb,
                                              const float* __restrict__ gw,
                                              u16* __restrict__ out){
  int row = blockIdx.x, tid = threadIdx.x;
  const uint4 yv = reinterpret_cast<const uint4*>(yh + (size_t)row*DINNER)[tid];
  const uint4 zv = reinterpret_cast<const uint4*>(zb + (size_t)row*DINNER)[tid];
  const unsigned* yp = (const unsigned*)&yv;
  const unsigned* zp = (const unsigned*)&zv;
  float t[8]; float ss = 0.f;
  #pragma unroll
  for (int i=0;i<4;i++){
    float y0 = b2f((u16)yp[i]), y1 = b2f((u16)(yp[i]>>16));
    float z0 = b2f((u16)zp[i]), z1 = b2f((u16)(zp[i]>>16));
    float v0 = y0 * (z0 / (1.f + expf(-z0)));
    float v1 = y1 * (z1 / (1.f + expf(-z1)));
    t[2*i] = v0; t[2*i+1] = v1; ss += v0*v0 + v1*v1;
  }
  #pragma unroll
  for (int off=32; off>0; off>>=1) ss += __shfl_down(ss, off, 64);
  __shared__ float red[4];
  if ((tid&63)==0) red[tid>>6] = ss;
  __syncthreads();
  float tot = red[0]+red[1]+red[2]+red[3];
  float g = rsqrtf(tot/(float)DINNER + 1e-5f);
  const float4 g0 = reinterpret_cast<const float4*>(gw)[tid*2];
  const float4 g1 = reinterpret_cast<const float4*>(gw)[tid*2+1];
  uint4 o;
  unsigned* op = (unsigned*)&o;
  float gg[8] = {g0.x,g0.y,g0.z,g0.w,g1.x,g1.y,g1.z,g1.w};
  #pragma unroll
  for (int i=0;i<4;i++)
    op[i] = (unsigned)f2b(t[2*i]*gg[2*i]*g) | ((unsigned)f2b(t[2*i+1]*gg[2*i+1]*g)<<16);
  reinterpret_cast<uint4*>(out + (size_t)row*DINNER)[tid] = o;
}

// ======== GEMM2: 128x128 tile, BK=64, 2-slot ring (64 KB), counted vmcnt ========
__global__ __launch_bounds__(256) void k_gemm2_64(const u16* __restrict__ A,
                                                  const u16* __restrict__ W,
                                                  const float* __restrict__ xres,
                                                  float* __restrict__ out){
  __shared__ __align__(16) u16 lds[2*16384];
  const int tid  = threadIdx.x;
  const int lane = tid & 63, wv = tid >> 6;
  const int wr = wv >> 1, wc = wv & 1;
  const int NWG = 8*32, Q = NWG/8;
  int swz = (blockIdx.x & 7)*Q + (blockIdx.x >> 3);
  int tm = swz / 8, tn = swz % 8;
  int m0 = tm*128, n0 = tn*128;
  const int K = DINNER;

  const int srow = tid >> 3;
  const int sslot = ((tid&7) ^ ((tid>>3)&7))*8;
  const u16* aSrc = A + (size_t)(m0 + srow)*K + sslot;
  const u16* bSrc = W + (size_t)(n0 + srow)*K + sslot;
  const int ldsu = wv*512;

  const int rr = lane & 15, gq = lane >> 4;

  f32x4 acc[4][4];
  #pragma unroll
  for (int i=0;i<4;i++)
    #pragma unroll
    for (int j=0;j<4;j++) acc[i][j] = (f32x4){0,0,0,0};

  auto STAGE = [&](int kt){
    u16* base = lds + (kt&1)*16384;
    #pragma unroll
    for (int j=0;j<4;j++)
      gload_lds16(aSrc + (size_t)(j*32)*K + kt*64, base + j*2048 + ldsu);
    #pragma unroll
    for (int j=0;j<4;j++)
      gload_lds16(bSrc + (size_t)(j*32)*K + kt*64, base + 8192 + j*2048 + ldsu);
  };
  auto KSTEP = [&](int kt, bool stg){
    const u16* bufA = lds + (kt&1)*16384;
    const u16* bufB = bufA + 8192;
    bf16x8 af[4][2], bw[4][2];
    #pragma unroll
    for (int t=0;t<4;t++){
      #pragma unroll
      for (int ks=0;ks<2;ks++){
        int sa = (ks*4 + gq) ^ (rr & 7);
        af[t][ks] = *(const bf16x8*)&bufA[(wr*64 + t*16 + rr)*64 + sa*8];
        bw[t][ks] = *(const bf16x8*)&bufB[(wc*64 + t*16 + rr)*64 + sa*8];
      }
    }
    asm volatile("s_waitcnt lgkmcnt(0)" ::: "memory");
    __builtin_amdgcn_s_barrier();
    if (stg) STAGE(kt+2);
    __builtin_amdgcn_s_setprio(1);
    #pragma unroll
    for (int ti=0;ti<4;ti++)
      #pragma unroll
      for (int tj=0;tj<4;tj++){
        acc[ti][tj] = MFMA16(af[ti][0], bw[tj][0], acc[ti][tj]);
        acc[ti][tj] = MFMA16(af[ti][1], bw[tj][1], acc[ti][tj]);
      }
    __builtin_amdgcn_s_setprio(0);
  };

  STAGE(0); STAGE(1);
  asm volatile("s_waitcnt vmcnt(8)" ::: "memory");
  __builtin_amdgcn_s_barrier();
  __builtin_amdgcn_sched_barrier(0);
  const int NT = K/64;
  for (int kt = 0; kt < NT-2; ++kt){
    KSTEP(kt, true);
    asm volatile("s_waitcnt vmcnt(8)" ::: "memory");
    __builtin_amdgcn_s_barrier();
    __builtin_amdgcn_sched_barrier(0);
  }
  KSTEP(NT-2, false);
  asm volatile("s_waitcnt vmcnt(0)" ::: "memory");
  __builtin_amdgcn_s_barrier();
  __builtin_amdgcn_sched_barrier(0);
  KSTEP(NT-1, false);

  int row0 = m0 + wr*64 + (lane>>4)*4;
  int col0 = n0 + wc*64 + (lane&15);
  #pragma unroll
  for (int ti=0;ti<4;ti++)
    #pragma unroll
    for (int tj=0;tj<4;tj++)
      #pragma unroll
      for (int q=0;q<4;q++){
        size_t idx = (size_t)(row0+ti*16+q)*DMODEL + col0 + tj*16;
        out[idx] = acc[ti][tj][q] + xres[idx];
      }
}

extern "C" void kernel_launch(void* const* d_in, const int* in_sizes, int n_in,
                              void* d_out, int out_size, void* d_ws, size_t ws_size,
                              hipStream_t stream) {
  (void)in_sizes; (void)n_in; (void)out_size; (void)ws_size;
  const float* x         = (const float*)d_in[0];
  const float* norm_w    = (const float*)d_in[1];
  const float* in_proj_w = (const float*)d_in[2];
  const float* conv_w    = (const float*)d_in[3];
  const float* conv_b    = (const float*)d_in[4];
  const float* dt_bias   = (const float*)d_in[5];
  const float* A_log     = (const float*)d_in[6];
  const float* D_skip    = (const float*)d_in[7];
  const float* gnorm_w   = (const float*)d_in[8];
  const float* out_proj_w= (const float*)d_in[9];
  float* out = (float*)d_out;

  char* ws = (char*)d_ws;
  size_t off = 0;
  auto alloc = [&](size_t bytes)->char*{
    char* p = ws + off; off = (off + bytes + 255) & ~(size_t)255; return p;
  };
  u16*   W2    = (u16*)  alloc((size_t)DMODEL*DINNER*2);
  u16*   zb    = (u16*)  alloc((size_t)NROWS*DINNER*2);
  float* dtraw = (float*)alloc((size_t)NROWS*NHEADS*4);
  float* dtT   = (float*)alloc((size_t)1024*128*4);
  float* cumT  = (float*)alloc((size_t)1024*128*4);
  u16*   xhb   = (u16*)  alloc((size_t)NROWS*DINNER*2);
  u16*   Bmb   = (u16*)  alloc((size_t)NROWS*4096*2);
  u16*   Cmb   = (u16*)  alloc((size_t)NROWS*4096*2);
  char*  R1    = alloc((size_t)NROWS*DXBC*2);
  u16*   xbcr  = (u16*)R1;
  u16*   S     = (u16*)R1;
  u16*   Hp    = (u16*)(R1 + (size_t)1024*8192*4);
  u16*   yh    = (u16*)R1;
  char*  R2    = alloc((size_t)DPROJ*DMODEL*2 + (size_t)NROWS*DMODEL*2);
  u16*   W1    = (u16*)R2;
  u16*   u_bf  = (u16*)(R2 + (size_t)DPROJ*DMODEL*2);
  u16*   gated = (u16*)R2;

  k_prep<<<2048+NROWS,256,0,stream>>>(in_proj_w, W1, DPROJ*DMODEL,
                                      out_proj_w, W2, DMODEL*DINNER,
                                      x, norm_w, u_bf);
  k_gemm_dt<<<NROWS/32,256,0,stream>>>(u_bf, W1, dtraw);
  k_gemm1_8p<<<768,512,0,stream>>>(u_bf, W1, zb, xbcr);
  k_convdt<<<2560+512,256,0,stream>>>(xbcr, conv_w, conv_b, xhb, Bmb, Cmb,
                                      dtraw, dt_bias, A_log, dtT, cumT);
  k_states<<<1024,512,0,stream>>>(Bmb, xhb, dtT, cumT, S);
  k_scan<<<256,256,0,stream>>>(S, cumT, Hp);
  k_intra<<<1024,512,0,stream>>>(Cmb, Bmb, xhb, Hp, dtT, cumT, D_skip, yh);
  k_gate<<<NROWS,256,0,stream>>>(yh, zb, gnorm_w, gated);
  k_gemm2_64<<<8*32,256,0,stream>>>(gated, W2, x, out);
}